// Round 1
// baseline (1492.222 us; speedup 1.0000x reference)
//
#include <hip/hip_runtime.h>
#include <cstdint>
#include <cstddef>

// Problem constants
constexpr int Bc  = 4;
constexpr int Sc  = 2048;
constexpr int DMc = 1024;   // d_model
constexpr int Hc  = 16;     // heads
constexpr int DHc = 64;     // head dim
constexpr int BHc = Bc * Hc;

typedef float f32x4  __attribute__((ext_vector_type(4)));
typedef short bf16x8 __attribute__((ext_vector_type(8)));

// f32 -> bf16 (RNE)
static __device__ __forceinline__ short f2bf(float x) {
  uint32_t u = __builtin_bit_cast(uint32_t, x);
  u += 0x7fffu + ((u >> 16) & 1u);
  return (short)(u >> 16);
}

static __device__ __forceinline__ f32x4 mfma16(bf16x8 a, bf16x8 b, f32x4 c) {
  return __builtin_amdgcn_mfma_f32_16x16x32_bf16(a, b, c, 0, 0, 0);
}

// load 8 consecutive f32 and convert to a bf16x8 fragment
static __device__ __forceinline__ bf16x8 cvt8(const float* __restrict__ p) {
  const float4* q = reinterpret_cast<const float4*>(p);
  float4 a = q[0], b = q[1];
  bf16x8 o;
  o[0] = f2bf(a.x); o[1] = f2bf(a.y); o[2] = f2bf(a.z); o[3] = f2bf(a.w);
  o[4] = f2bf(b.x); o[5] = f2bf(b.y); o[6] = f2bf(b.z); o[7] = f2bf(b.w);
  return o;
}

// ---------------- dtype conversion: f32 -> bf16, 4 elems/thread ----------------
__global__ __launch_bounds__(256) void k_cvt(const float* __restrict__ in,
                                             short* __restrict__ out) {
  int i = blockIdx.x * 256 + threadIdx.x;
  float4 v = reinterpret_cast<const float4*>(in)[i];
  short4 o;
  o.x = f2bf(v.x); o.y = f2bf(v.y); o.z = f2bf(v.z); o.w = f2bf(v.w);
  reinterpret_cast<short4*>(out)[i] = o;
}

// ---------------- GEMM: Y[m,e] = sum_d A[m,d] * Bt[e,d] ----------------
// A: bf16 [M=8192][K=1024] row-major; Bt: bf16 [N=1024][K=1024] row-major (K-major).
// mode 0: out bf16 [BH][S][64] (Q/K proj)
// mode 1: out bf16 [BH][64][S] (V proj, transposed)
// mode 2: out f32  [M][1024]   (output proj)
__global__ __launch_bounds__(256) void k_gemm(const short* __restrict__ A,
                                              const short* __restrict__ Bt,
                                              void* __restrict__ out, int mode) {
  const int bm = blockIdx.x * 64, bn = blockIdx.y * 64;
  const int lane = threadIdx.x & 63, w = threadIdx.x >> 6;   // 4 waves
  const int r = lane & 15, g = lane >> 4;                    // frag row/col, k-group
  const int arow = bm + w * 16 + r;

  f32x4 acc[4] = {};
  const short* ap = A + (size_t)arow * DMc;
  #pragma unroll 4
  for (int k0 = 0; k0 < DMc; k0 += 32) {
    bf16x8 af = *reinterpret_cast<const bf16x8*>(ap + k0 + g * 8);
    #pragma unroll
    for (int n = 0; n < 4; n++) {
      bf16x8 bf = *reinterpret_cast<const bf16x8*>(
          Bt + (size_t)(bn + n * 16 + r) * DMc + k0 + g * 8);
      acc[n] = mfma16(af, bf, acc[n]);
    }
  }

  #pragma unroll
  for (int n = 0; n < 4; n++) {
    const int col = bn + n * 16 + r;
    #pragma unroll
    for (int j = 0; j < 4; j++) {
      const int m = bm + w * 16 + g * 4 + j;
      if (mode == 2) {
        reinterpret_cast<float*>(out)[(size_t)m * DMc + col] = acc[n][j];
      } else {
        const int b = m >> 11, s = m & (Sc - 1);
        const int h = col >> 6, d = col & (DHc - 1);
        size_t idx = (mode == 1)
            ? ((size_t)(b * Hc + h) * DHc + d) * Sc + s     // Vt [BH][64][S]
            : ((size_t)(b * Hc + h) * Sc + s) * DHc + d;    // Q/K [BH][S][64]
        reinterpret_cast<short*>(out)[idx] = f2bf(acc[n][j]);
      }
    }
  }
}

// ---------------- scores + mask + softmax -> attn (f32, to d_out) ----------------
// grid (S/16, BH), block 512 (8 waves). Each block: 16 q-rows, full 2048 k-cols.
// Wave w covers cols [w*256, w*256+256) as 16 col-tiles.
__global__ __launch_bounds__(512) void k_scores(const short* __restrict__ Qb,
                                                const short* __restrict__ Kb,
                                                const int* __restrict__ mask,
                                                float* __restrict__ attn) {
  const int qb = blockIdx.x * 16;
  const int bh = blockIdx.y;
  const int b  = bh >> 4;
  const int lane = threadIdx.x & 63, w = threadIdx.x >> 6;  // 8 waves
  const int r = lane & 15, g = lane >> 4;

  const short* qrow = Qb + ((size_t)bh * Sc + qb + r) * DHc;
  const bf16x8 qa0 = *reinterpret_cast<const bf16x8*>(qrow + g * 8);
  const bf16x8 qa1 = *reinterpret_cast<const bf16x8*>(qrow + g * 8 + 32);
  const short* kbase = Kb + (size_t)bh * Sc * DHc;

  f32x4 sc[16];
  #pragma unroll
  for (int t = 0; t < 16; t++) {
    const int kc = (w * 16 + t) * 16 + r;
    const short* krow = kbase + (size_t)kc * DHc;
    bf16x8 kb0 = *reinterpret_cast<const bf16x8*>(krow + g * 8);
    bf16x8 kb1 = *reinterpret_cast<const bf16x8*>(krow + g * 8 + 32);
    f32x4 a = {};
    a = mfma16(qa0, kb0, a);
    a = mfma16(qa1, kb1, a);
    sc[t] = a;
  }

  // scale + mask (True/nonzero = masked -> -1e9)
  const int* mbase = mask + (size_t)b * Sc * Sc;
  #pragma unroll
  for (int t = 0; t < 16; t++) {
    const int kc = (w * 16 + t) * 16 + r;
    #pragma unroll
    for (int j = 0; j < 4; j++) {
      const int q = qb + g * 4 + j;
      float s = sc[t][j] * 0.125f;
      if (mbase[(size_t)q * Sc + kc] != 0) s = -1e9f;
      sc[t][j] = s;
    }
  }

  __shared__ float redm[8][16];
  __shared__ float reds[8][16];

  // per-row max: in-reg over 16 tiles, butterfly over 16 lanes, LDS over 8 waves
  float pm[4] = {-3e38f, -3e38f, -3e38f, -3e38f};
  #pragma unroll
  for (int t = 0; t < 16; t++)
    #pragma unroll
    for (int j = 0; j < 4; j++) pm[j] = fmaxf(pm[j], sc[t][j]);
  #pragma unroll
  for (int j = 0; j < 4; j++)
    #pragma unroll
    for (int m2 = 1; m2 < 16; m2 <<= 1) pm[j] = fmaxf(pm[j], __shfl_xor(pm[j], m2));
  if (r == 0) {
    #pragma unroll
    for (int j = 0; j < 4; j++) redm[w][g * 4 + j] = pm[j];
  }
  __syncthreads();
  float rmax[4];
  #pragma unroll
  for (int j = 0; j < 4; j++) {
    float v = redm[0][g * 4 + j];
    #pragma unroll
    for (int ww = 1; ww < 8; ww++) v = fmaxf(v, redm[ww][g * 4 + j]);
    rmax[j] = v;
  }

  // exp + per-row sum
  float psum[4] = {0.f, 0.f, 0.f, 0.f};
  #pragma unroll
  for (int t = 0; t < 16; t++)
    #pragma unroll
    for (int j = 0; j < 4; j++) {
      float e = __expf(sc[t][j] - rmax[j]);
      sc[t][j] = e;
      psum[j] += e;
    }
  #pragma unroll
  for (int j = 0; j < 4; j++)
    #pragma unroll
    for (int m2 = 1; m2 < 16; m2 <<= 1) psum[j] += __shfl_xor(psum[j], m2);
  if (r == 0) {
    #pragma unroll
    for (int j = 0; j < 4; j++) reds[w][g * 4 + j] = psum[j];
  }
  __syncthreads();
  float rinv[4];
  #pragma unroll
  for (int j = 0; j < 4; j++) {
    float v = 0.f;
    #pragma unroll
    for (int ww = 0; ww < 8; ww++) v += reds[ww][g * 4 + j];
    rinv[j] = 1.0f / v;
  }

  // write attn f32
  float* abase = attn + ((size_t)bh * Sc + qb) * Sc;
  #pragma unroll
  for (int t = 0; t < 16; t++) {
    const int kc = (w * 16 + t) * 16 + r;
    #pragma unroll
    for (int j = 0; j < 4; j++)
      abase[(size_t)(g * 4 + j) * Sc + kc] = sc[t][j] * rinv[j];
  }
}

// ---------------- context = attn @ V ----------------
// grid (S/64, BH), block 256 (4 waves). Vt: bf16 [BH][64][S]. ctx: bf16 [B][S][1024].
__global__ __launch_bounds__(256) void k_pv(const float* __restrict__ attn,
                                            const short* __restrict__ Vt,
                                            short* __restrict__ ctx) {
  const int q0 = blockIdx.x * 64;
  const int bh = blockIdx.y;
  const int b = bh >> 4, h = bh & 15;
  const int lane = threadIdx.x & 63, w = threadIdx.x >> 6;
  const int r = lane & 15, g = lane >> 4;

  const float* arow = attn + ((size_t)bh * Sc + q0 + w * 16 + r) * Sc;
  const short* vb = Vt + (size_t)bh * DHc * Sc;

  f32x4 acc[4] = {};
  for (int k0 = 0; k0 < Sc; k0 += 32) {
    const bf16x8 af = cvt8(arow + k0 + g * 8);
    #pragma unroll
    for (int n = 0; n < 4; n++) {
      bf16x8 bf = *reinterpret_cast<const bf16x8*>(
          vb + (size_t)(n * 16 + r) * Sc + k0 + g * 8);
      acc[n] = mfma16(af, bf, acc[n]);
    }
  }

  #pragma unroll
  for (int n = 0; n < 4; n++) {
    const int d = n * 16 + r;
    #pragma unroll
    for (int j = 0; j < 4; j++) {
      const int s = q0 + w * 16 + g * 4 + j;
      ctx[((size_t)b * Sc + s) * DMc + h * DHc + d] = f2bf(acc[n][j]);
    }
  }
}

// ---------------- residual + LayerNorm ----------------
// grid (B*S), block 256; 4 f32 per thread.
__global__ __launch_bounds__(256) void k_ln(const float* __restrict__ y,
                                            const float* __restrict__ resid,
                                            float* __restrict__ out) {
  const int m = blockIdx.x, t = threadIdx.x;
  const float4 a = reinterpret_cast<const float4*>(y + (size_t)m * DMc)[t];
  const float4 b = reinterpret_cast<const float4*>(resid + (size_t)m * DMc)[t];
  float x0 = a.x + b.x, x1 = a.y + b.y, x2 = a.z + b.z, x3 = a.w + b.w;

  float s = x0 + x1 + x2 + x3;
  #pragma unroll
  for (int m2 = 1; m2 < 64; m2 <<= 1) s += __shfl_xor(s, m2);
  __shared__ float red[4];
  __shared__ float red2[4];
  const int w = t >> 6, lane = t & 63;
  if (lane == 0) red[w] = s;
  __syncthreads();
  const float mean = (red[0] + red[1] + red[2] + red[3]) * (1.0f / DMc);

  x0 -= mean; x1 -= mean; x2 -= mean; x3 -= mean;
  float s2 = x0 * x0 + x1 * x1 + x2 * x2 + x3 * x3;
  #pragma unroll
  for (int m2 = 1; m2 < 64; m2 <<= 1) s2 += __shfl_xor(s2, m2);
  if (lane == 0) red2[w] = s2;
  __syncthreads();
  const float var = (red2[0] + red2[1] + red2[2] + red2[3]) * (1.0f / DMc);
  const float rstd = rsqrtf(var + 1e-5f);

  float4 o;
  o.x = x0 * rstd; o.y = x1 * rstd; o.z = x2 * rstd; o.w = x3 * rstd;
  reinterpret_cast<float4*>(out + (size_t)m * DMc)[t] = o;
}

extern "C" void kernel_launch(void* const* d_in, const int* in_sizes, int n_in,
                              void* d_out, int out_size, void* d_ws, size_t ws_size,
                              hipStream_t stream) {
  const float* inQ = (const float*)d_in[0];
  const float* inK = (const float*)d_in[1];
  const float* inV = (const float*)d_in[2];
  const int*   msk = (const int*)d_in[3];
  const float* WQ  = (const float*)d_in[4];
  const float* WK  = (const float*)d_in[5];
  const float* WV  = (const float*)d_in[6];
  const float* Wfc = (const float*)d_in[7];

  float* out_ln   = (float*)d_out;                       // [B,S,1024] f32
  float* out_attn = out_ln + (size_t)Bc * Sc * DMc;      // [B,H,S,S] f32

  // workspace layout (bytes): total 125,829,120 (120 MiB)
  const size_t NX = (size_t)Bc * Sc * DMc;  // 8,388,608 elems
  const size_t NW = (size_t)DMc * DMc;      // 1,048,576 elems
  short* XbQ = (short*)d_ws;       // bf16 inputs
  short* XbK = XbQ + NX;
  short* XbV = XbK + NX;
  short* WQb = XbV + NX;           // bf16 weights
  short* WKb = WQb + NW;
  short* WVb = WKb + NW;
  short* Wfb = WVb + NW;
  short* Qb  = Wfb + NW;           // [BH][S][64]
  short* Kb  = Qb + NX;            // [BH][S][64]
  short* Vt  = Kb + NX;            // [BH][64][S]
  short* ctx = Vt + NX;            // [B][S][1024]
  float* y   = (float*)d_ws;       // f32 [8192][1024], aliases XbQ+XbK (dead then)

  // 1) f32 -> bf16 conversions
  k_cvt<<<dim3((unsigned)(NX / 1024)), 256, 0, stream>>>(inQ, XbQ);
  k_cvt<<<dim3((unsigned)(NX / 1024)), 256, 0, stream>>>(inK, XbK);
  k_cvt<<<dim3((unsigned)(NX / 1024)), 256, 0, stream>>>(inV, XbV);
  k_cvt<<<dim3((unsigned)(NW / 1024)), 256, 0, stream>>>(WQ, WQb);
  k_cvt<<<dim3((unsigned)(NW / 1024)), 256, 0, stream>>>(WK, WKb);
  k_cvt<<<dim3((unsigned)(NW / 1024)), 256, 0, stream>>>(WV, WVb);
  k_cvt<<<dim3((unsigned)(NW / 1024)), 256, 0, stream>>>(Wfc, Wfb);

  // 2) projections
  dim3 gp(Bc * Sc / 64, DMc / 64);  // (128, 16)
  k_gemm<<<gp, 256, 0, stream>>>(XbQ, WQb, (void*)Qb, 0);
  k_gemm<<<gp, 256, 0, stream>>>(XbK, WKb, (void*)Kb, 0);
  k_gemm<<<gp, 256, 0, stream>>>(XbV, WVb, (void*)Vt, 1);

  // 3) scores + mask + softmax -> attn (output 1)
  k_scores<<<dim3(Sc / 16, BHc), 512, 0, stream>>>(Qb, Kb, msk, out_attn);

  // 4) context = attn @ V
  k_pv<<<dim3(Sc / 64, BHc), 256, 0, stream>>>(out_attn, Vt, ctx);

  // 5) output projection -> y (f32)
  k_gemm<<<gp, 256, 0, stream>>>(ctx, Wfb, (void*)y, 2);

  // 6) residual + LayerNorm -> ln (output 0)
  k_ln<<<dim3(Bc * Sc), 256, 0, stream>>>(y, inQ, out_ln);
}

// Round 2
// 980.903 us; speedup vs baseline: 1.5213x; 1.5213x over previous
//
#include <hip/hip_runtime.h>
#include <cstdint>
#include <cstddef>

// Problem constants
constexpr int Bc  = 4;
constexpr int Sc  = 2048;
constexpr int DMc = 1024;   // d_model
constexpr int Hc  = 16;     // heads
constexpr int DHc = 64;     // head dim
constexpr int BHc = Bc * Hc;

typedef float f32x4  __attribute__((ext_vector_type(4)));
typedef short bf16x8 __attribute__((ext_vector_type(8)));

// f32 -> bf16 (RNE)
static __device__ __forceinline__ short f2bf(float x) {
  uint32_t u = __builtin_bit_cast(uint32_t, x);
  u += 0x7fffu + ((u >> 16) & 1u);
  return (short)(u >> 16);
}

static __device__ __forceinline__ f32x4 mfma16(bf16x8 a, bf16x8 b, f32x4 c) {
  return __builtin_amdgcn_mfma_f32_16x16x32_bf16(a, b, c, 0, 0, 0);
}

// load 8 consecutive f32 and convert to a bf16x8 fragment
static __device__ __forceinline__ bf16x8 cvt8(const float* __restrict__ p) {
  const float4* q = reinterpret_cast<const float4*>(p);
  float4 a = q[0], b = q[1];
  bf16x8 o;
  o[0] = f2bf(a.x); o[1] = f2bf(a.y); o[2] = f2bf(a.z); o[3] = f2bf(a.w);
  o[4] = f2bf(b.x); o[5] = f2bf(b.y); o[6] = f2bf(b.z); o[7] = f2bf(b.w);
  return o;
}

// async global->LDS, 16B per lane. LDS dest must be wave-uniform base;
// HW writes lane i at base + i*16. Global src is per-lane.
static __device__ __forceinline__ void gload16(const short* g, short* l) {
  __builtin_amdgcn_global_load_lds(
      (const __attribute__((address_space(1))) void*)g,
      (__attribute__((address_space(3))) void*)l, 16, 0, 0);
}

// ---------------- dtype conversion: f32 -> bf16, 4 elems/thread ----------------
__global__ __launch_bounds__(256) void k_cvt(const float* __restrict__ in,
                                             short* __restrict__ out) {
  int i = blockIdx.x * 256 + threadIdx.x;
  float4 v = reinterpret_cast<const float4*>(in)[i];
  short4 o;
  o.x = f2bf(v.x); o.y = f2bf(v.y); o.z = f2bf(v.z); o.w = f2bf(v.w);
  reinterpret_cast<short4*>(out)[i] = o;
}

// ---------------- mask bit-pack: int32 -> 1 bit ----------------
__global__ __launch_bounds__(256) void k_pack(const int* __restrict__ m,
                                              uint32_t* __restrict__ bits) {
  size_t i = (size_t)blockIdx.x * 256 + threadIdx.x;
  uint64_t b = __ballot(m[i] != 0);
  int lane = threadIdx.x & 63;
  if (lane == 0)  bits[i >> 5] = (uint32_t)b;
  if (lane == 32) bits[i >> 5] = (uint32_t)(b >> 32);
}

// ---------------- GEMM: Y[m,e] = sum_d A[m,d] * Bt[e,d] ----------------
// 128x128 tile, BK=32, 256 threads (4 waves, 2x2), each wave 64x64.
// LDS staged via global_load_lds(16B); slot-XOR swizzle (slot ^= (row>>1)&3)
// applied on the GLOBAL source + on the ds_read address (both-sides rule).
// mode 0: out bf16 [BH][S][64]; mode 1: out bf16 [BH][64][S]; mode 2: out f32 [M][1024].
__global__ __launch_bounds__(256) void k_gemm(const short* __restrict__ A,
                                              const short* __restrict__ Bt,
                                              void* __restrict__ out, int mode) {
  __shared__ __align__(16) short lA[128 * 32];
  __shared__ __align__(16) short lB[128 * 32];
  const int bm = blockIdx.x * 128, bn = blockIdx.y * 128;
  const int lane = threadIdx.x & 63, w = threadIdx.x >> 6;
  const int wr = w >> 1, wc = w & 1;
  const int r = lane & 15, g = lane >> 4;
  const int lrow = lane >> 2;                       // staging row within 16-row chunk
  const int lsl  = (lane & 3) ^ ((lane >> 3) & 3);  // pre-swizzled global k-slot
  const int rsw  = (r >> 1) & 3;                    // read-side swizzle

  f32x4 acc[4][4] = {};
  const short* Ab = A + (size_t)bm * DMc;
  const short* Bb = Bt + (size_t)bn * DMc;

  for (int k0 = 0; k0 < DMc; k0 += 32) {
    __syncthreads();  // protect LDS from previous iteration's readers
    #pragma unroll
    for (int c = 0; c < 2; c++) {
      const int rbase = c * 64 + w * 16;
      gload16(Ab + (size_t)(rbase + lrow) * DMc + k0 + lsl * 8, lA + rbase * 32);
      gload16(Bb + (size_t)(rbase + lrow) * DMc + k0 + lsl * 8, lB + rbase * 32);
    }
    __syncthreads();  // compiler drains vmcnt before barrier -> staged data ready

    bf16x8 af[4], bfr[4];
    #pragma unroll
    for (int i = 0; i < 4; i++) {
      const int arow = wr * 64 + i * 16 + r;
      af[i]  = *reinterpret_cast<const bf16x8*>(lA + arow * 32 + (g ^ rsw) * 8);
      const int brow = wc * 64 + i * 16 + r;
      bfr[i] = *reinterpret_cast<const bf16x8*>(lB + brow * 32 + (g ^ rsw) * 8);
    }
    #pragma unroll
    for (int i = 0; i < 4; i++)
      #pragma unroll
      for (int n = 0; n < 4; n++) acc[i][n] = mfma16(af[i], bfr[n], acc[i][n]);
  }

  #pragma unroll
  for (int i = 0; i < 4; i++) {
    #pragma unroll
    for (int n = 0; n < 4; n++) {
      const int col = bn + wc * 64 + n * 16 + r;
      #pragma unroll
      for (int j = 0; j < 4; j++) {
        const int m = bm + wr * 64 + i * 16 + g * 4 + j;
        if (mode == 2) {
          reinterpret_cast<float*>(out)[(size_t)m * DMc + col] = acc[i][n][j];
        } else {
          const int b = m >> 11, s = m & (Sc - 1);
          const int h = col >> 6, d = col & (DHc - 1);
          size_t idx = (mode == 1)
              ? ((size_t)(b * Hc + h) * DHc + d) * Sc + s     // Vt [BH][64][S]
              : ((size_t)(b * Hc + h) * Sc + s) * DHc + d;    // Q/K [BH][S][64]
          reinterpret_cast<short*>(out)[idx] = f2bf(acc[i][n][j]);
        }
      }
    }
  }
}

// ---------------- fused scores + mask + softmax + attn-write + PV ----------------
// grid (S/16, BH), block 512 (8 waves). Block: 16 q-rows, full 2048 k-cols.
// Wave w owns k-cols [w*256, w*256+256): computes scores, writes normalized attn,
// re-reads its own freshly written 16x256 block (L1/L2 RAW after vmcnt(0)) as the
// PV A-operand, accumulates partial ctx[16][64], cross-wave reduce via LDS.
__global__ __launch_bounds__(512, 4) void k_attn(const short* __restrict__ Qb,
                                                 const short* __restrict__ Kb,
                                                 const uint32_t* __restrict__ pbits,
                                                 const short* __restrict__ Vt,
                                                 float* __restrict__ attn,
                                                 short* __restrict__ ctx) {
  const int qb = blockIdx.x * 16;
  const int bh = blockIdx.y;
  const int b = bh >> 4, h = bh & 15;
  const int lane = threadIdx.x & 63, w = threadIdx.x >> 6;
  const int r = lane & 15, g = lane >> 4;

  const short* qrow = Qb + ((size_t)bh * Sc + qb + r) * DHc;
  const bf16x8 qa0 = *reinterpret_cast<const bf16x8*>(qrow + g * 8);
  const bf16x8 qa1 = *reinterpret_cast<const bf16x8*>(qrow + g * 8 + 32);
  const short* kbase = Kb + (size_t)bh * Sc * DHc;

  // QK^T: 16 col-tiles of 16, K=64 as 2 MFMAs
  f32x4 sc[16];
  #pragma unroll
  for (int t = 0; t < 16; t++) {
    const short* krow = kbase + (size_t)((w * 16 + t) * 16 + r) * DHc;
    bf16x8 kb0 = *reinterpret_cast<const bf16x8*>(krow + g * 8);
    bf16x8 kb1 = *reinterpret_cast<const bf16x8*>(krow + g * 8 + 32);
    f32x4 a = {};
    a = mfma16(qa0, kb0, a);
    a = mfma16(qa1, kb1, a);
    sc[t] = a;
  }

  // scale + packed-mask apply (word tp covers cols [w*256+tp*32, +32))
  #pragma unroll
  for (int tp = 0; tp < 8; tp++) {
    #pragma unroll
    for (int j = 0; j < 4; j++) {
      const uint32_t mword =
          pbits[((size_t)b * Sc + qb + g * 4 + j) * (Sc / 32) + w * 8 + tp];
      float s0 = sc[2 * tp][j] * 0.125f;
      if ((mword >> r) & 1u) s0 = -1e9f;
      sc[2 * tp][j] = s0;
      float s1 = sc[2 * tp + 1][j] * 0.125f;
      if ((mword >> (16 + r)) & 1u) s1 = -1e9f;
      sc[2 * tp + 1][j] = s1;
    }
  }

  __shared__ float redm[8][16];
  __shared__ float reds[8][16];

  // row max
  float pm[4] = {-3e38f, -3e38f, -3e38f, -3e38f};
  #pragma unroll
  for (int t = 0; t < 16; t++)
    #pragma unroll
    for (int j = 0; j < 4; j++) pm[j] = fmaxf(pm[j], sc[t][j]);
  #pragma unroll
  for (int j = 0; j < 4; j++)
    #pragma unroll
    for (int m2 = 1; m2 < 16; m2 <<= 1) pm[j] = fmaxf(pm[j], __shfl_xor(pm[j], m2));
  if (r == 0) {
    #pragma unroll
    for (int j = 0; j < 4; j++) redm[w][g * 4 + j] = pm[j];
  }
  __syncthreads();
  float rmax[4];
  #pragma unroll
  for (int j = 0; j < 4; j++) {
    float v = redm[0][g * 4 + j];
    #pragma unroll
    for (int ww = 1; ww < 8; ww++) v = fmaxf(v, redm[ww][g * 4 + j]);
    rmax[j] = v;
  }

  // exp + row sum
  float psum[4] = {0.f, 0.f, 0.f, 0.f};
  #pragma unroll
  for (int t = 0; t < 16; t++)
    #pragma unroll
    for (int j = 0; j < 4; j++) {
      float e = __expf(sc[t][j] - rmax[j]);
      sc[t][j] = e;
      psum[j] += e;
    }
  #pragma unroll
  for (int j = 0; j < 4; j++)
    #pragma unroll
    for (int m2 = 1; m2 < 16; m2 <<= 1) psum[j] += __shfl_xor(psum[j], m2);
  if (r == 0) {
    #pragma unroll
    for (int j = 0; j < 4; j++) reds[w][g * 4 + j] = psum[j];
  }
  __syncthreads();
  float rinv[4];
  #pragma unroll
  for (int j = 0; j < 4; j++) {
    float v = 0.f;
    #pragma unroll
    for (int ww = 0; ww < 8; ww++) v += reds[ww][g * 4 + j];
    rinv[j] = 1.0f / v;
  }

  // write normalized attn (output 1)
  float* abase = attn + ((size_t)bh * Sc + qb) * Sc;
  #pragma unroll
  for (int t = 0; t < 16; t++) {
    const int kc = (w * 16 + t) * 16 + r;
    #pragma unroll
    for (int j = 0; j < 4; j++)
      abase[(size_t)(g * 4 + j) * Sc + kc] = sc[t][j] * rinv[j];
  }
  // same-wave RAW: drain stores to L2 before re-reading our own block
  asm volatile("s_waitcnt vmcnt(0)" ::: "memory");

  // PV over this wave's k-window; A-frag = re-read of our own attn rows
  const float* arow = abase + (size_t)r * Sc + w * 256;  // attn[qb+r][w*256 ...]
  const short* vb = Vt + (size_t)bh * DHc * Sc;
  f32x4 pacc[4] = {};
  #pragma unroll
  for (int kt = 0; kt < 8; kt++) {
    const bf16x8 af = cvt8(arow + kt * 32 + g * 8);
    #pragma unroll
    for (int n = 0; n < 4; n++) {
      bf16x8 vf = *reinterpret_cast<const bf16x8*>(
          vb + (size_t)(n * 16 + r) * Sc + w * 256 + kt * 32 + g * 8);
      pacc[n] = mfma16(af, vf, pacc[n]);
    }
  }

  // cross-wave reduce of partial ctx[16][64] (d-stride padded to 65)
  __shared__ float rbuf[8][16][65];
  #pragma unroll
  for (int n = 0; n < 4; n++)
    #pragma unroll
    for (int j = 0; j < 4; j++) rbuf[w][g * 4 + j][n * 16 + r] = pacc[n][j];
  __syncthreads();

  const int tq = threadIdx.x >> 5, td = (threadIdx.x & 31) * 2;
  float s0 = 0.f, s1 = 0.f;
  #pragma unroll
  for (int ww = 0; ww < 8; ww++) {
    s0 += rbuf[ww][tq][td];
    s1 += rbuf[ww][tq][td + 1];
  }
  uint32_t pk = (uint32_t)(uint16_t)f2bf(s0) | ((uint32_t)(uint16_t)f2bf(s1) << 16);
  *reinterpret_cast<uint32_t*>(ctx + ((size_t)b * Sc + qb + tq) * DMc + h * DHc + td) = pk;
}

// ---------------- residual + LayerNorm ----------------
__global__ __launch_bounds__(256) void k_ln(const float* __restrict__ y,
                                            const float* __restrict__ resid,
                                            float* __restrict__ out) {
  const int m = blockIdx.x, t = threadIdx.x;
  const float4 a = reinterpret_cast<const float4*>(y + (size_t)m * DMc)[t];
  const float4 b = reinterpret_cast<const float4*>(resid + (size_t)m * DMc)[t];
  float x0 = a.x + b.x, x1 = a.y + b.y, x2 = a.z + b.z, x3 = a.w + b.w;

  float s = x0 + x1 + x2 + x3;
  #pragma unroll
  for (int m2 = 1; m2 < 64; m2 <<= 1) s += __shfl_xor(s, m2);
  __shared__ float red[4];
  __shared__ float red2[4];
  const int w = t >> 6, lane = t & 63;
  if (lane == 0) red[w] = s;
  __syncthreads();
  const float mean = (red[0] + red[1] + red[2] + red[3]) * (1.0f / DMc);

  x0 -= mean; x1 -= mean; x2 -= mean; x3 -= mean;
  float s2 = x0 * x0 + x1 * x1 + x2 * x2 + x3 * x3;
  #pragma unroll
  for (int m2 = 1; m2 < 64; m2 <<= 1) s2 += __shfl_xor(s2, m2);
  if (lane == 0) red2[w] = s2;
  __syncthreads();
  const float var = (red2[0] + red2[1] + red2[2] + red2[3]) * (1.0f / DMc);
  const float rstd = rsqrtf(var + 1e-5f);

  float4 o;
  o.x = x0 * rstd; o.y = x1 * rstd; o.z = x2 * rstd; o.w = x3 * rstd;
  reinterpret_cast<float4*>(out + (size_t)m * DMc)[t] = o;
}

extern "C" void kernel_launch(void* const* d_in, const int* in_sizes, int n_in,
                              void* d_out, int out_size, void* d_ws, size_t ws_size,
                              hipStream_t stream) {
  const float* inQ = (const float*)d_in[0];
  const float* inK = (const float*)d_in[1];
  const float* inV = (const float*)d_in[2];
  const int*   msk = (const int*)d_in[3];
  const float* WQ  = (const float*)d_in[4];
  const float* WK  = (const float*)d_in[5];
  const float* WV  = (const float*)d_in[6];
  const float* Wfc = (const float*)d_in[7];

  float* out_ln   = (float*)d_out;                       // [B,S,1024] f32
  float* out_attn = out_ln + (size_t)Bc * Sc * DMc;      // [B,H,S,S] f32

  // workspace (shorts): 6*NX + 4*NW + 1M (pbits) = ~110.8 MiB
  const size_t NX = (size_t)Bc * Sc * DMc;  // 8,388,608
  const size_t NW = (size_t)DMc * DMc;      // 1,048,576
  short* ws = (short*)d_ws;
  short* XbQ = ws;                 // bf16 inputs
  short* XbK = XbQ + NX;
  short* XbV = XbK + NX;
  short* WQb = XbV + NX;           // bf16 weights
  short* WKb = WQb + NW;
  short* WVb = WKb + NW;
  short* Wfb = WVb + NW;
  short* Qb  = Wfb + NW;           // [BH][S][64]
  short* Kb  = Qb + NX;            // [BH][S][64]
  short* Vt  = Kb + NX;            // [BH][64][S]
  uint32_t* pbits = (uint32_t*)(Vt + NX);  // [B][S][64 words]
  short* ctx = XbV;                // aliases XbV (dead after V-proj)
  float* y   = (float*)XbQ;        // aliases XbQ+XbK (dead after Q/K-proj)

  // 1) f32 -> bf16 conversions + mask pack
  k_cvt<<<dim3((unsigned)(NX / 1024)), 256, 0, stream>>>(inQ, XbQ);
  k_cvt<<<dim3((unsigned)(NX / 1024)), 256, 0, stream>>>(inK, XbK);
  k_cvt<<<dim3((unsigned)(NX / 1024)), 256, 0, stream>>>(inV, XbV);
  k_cvt<<<dim3((unsigned)(NW / 1024)), 256, 0, stream>>>(WQ, WQb);
  k_cvt<<<dim3((unsigned)(NW / 1024)), 256, 0, stream>>>(WK, WKb);
  k_cvt<<<dim3((unsigned)(NW / 1024)), 256, 0, stream>>>(WV, WVb);
  k_cvt<<<dim3((unsigned)(NW / 1024)), 256, 0, stream>>>(Wfc, Wfb);
  k_pack<<<dim3((unsigned)(Bc * Sc * (Sc / 256))), 256, 0, stream>>>(msk, pbits);

  // 2) projections (128x128 tiles)
  dim3 gp(Bc * Sc / 128, DMc / 128);  // (64, 8)
  k_gemm<<<gp, 256, 0, stream>>>(XbQ, WQb, (void*)Qb, 0);
  k_gemm<<<gp, 256, 0, stream>>>(XbK, WKb, (void*)Kb, 0);
  k_gemm<<<gp, 256, 0, stream>>>(XbV, WVb, (void*)Vt, 1);

  // 3) fused scores + softmax + attn write + PV -> ctx
  k_attn<<<dim3(Sc / 16, BHc), 512, 0, stream>>>(Qb, Kb, pbits, Vt, out_attn, ctx);

  // 4) output projection -> y (f32)
  k_gemm<<<gp, 256, 0, stream>>>(ctx, Wfb, (void*)y, 2);

  // 5) residual + LayerNorm -> ln (output 0)
  k_ln<<<dim3(Bc * Sc), 256, 0, stream>>>(y, inQ, out_ln);
}

// Round 4
// 800.035 us; speedup vs baseline: 1.8652x; 1.2261x over previous
//
#include <hip/hip_runtime.h>
#include <cstdint>
#include <cstddef>

// Problem constants
constexpr int Bc  = 4;
constexpr int Sc  = 2048;
constexpr int DMc = 1024;   // d_model
constexpr int Hc  = 16;     // heads
constexpr int DHc = 64;     // head dim
constexpr int BHc = Bc * Hc;

typedef float f32x4  __attribute__((ext_vector_type(4)));
typedef short bf16x8 __attribute__((ext_vector_type(8)));

// f32 -> bf16 (RNE)
static __device__ __forceinline__ short f2bf(float x) {
  uint32_t u = __builtin_bit_cast(uint32_t, x);
  u += 0x7fffu + ((u >> 16) & 1u);
  return (short)(u >> 16);
}

static __device__ __forceinline__ f32x4 mfma16(bf16x8 a, bf16x8 b, f32x4 c) {
  return __builtin_amdgcn_mfma_f32_16x16x32_bf16(a, b, c, 0, 0, 0);
}

// async global->LDS, 16B per lane. LDS dest is wave-uniform base + lane*16.
static __device__ __forceinline__ void gload16(const short* g, short* l) {
  __builtin_amdgcn_global_load_lds(
      (const __attribute__((address_space(1))) void*)g,
      (__attribute__((address_space(3))) void*)l, 16, 0, 0);
}

// ---------------- dtype conversion: f32 -> bf16, 4 elems/thread ----------------
__global__ __launch_bounds__(256) void k_cvt(const float* __restrict__ in,
                                             short* __restrict__ out) {
  int i = blockIdx.x * 256 + threadIdx.x;
  float4 v = reinterpret_cast<const float4*>(in)[i];
  short4 o;
  o.x = f2bf(v.x); o.y = f2bf(v.y); o.z = f2bf(v.z); o.w = f2bf(v.w);
  reinterpret_cast<short4*>(out)[i] = o;
}

// ---------------- mask bit-pack: int32 -> 1 bit ----------------
__global__ __launch_bounds__(256) void k_pack(const int* __restrict__ m,
                                              uint32_t* __restrict__ bits) {
  size_t i = (size_t)blockIdx.x * 256 + threadIdx.x;
  uint64_t b = __ballot(m[i] != 0);
  int lane = threadIdx.x & 63;
  if (lane == 0)  bits[i >> 5] = (uint32_t)b;
  if (lane == 32) bits[i >> 5] = (uint32_t)(b >> 32);
}

// ---------------- GEMM: Y[m,e] = sum_d A[m,d] * Bt[e,d] ----------------
// 128x128 tile, BK=32, 256 threads (4 waves, 2x2), each wave 64x64.
__global__ __launch_bounds__(256) void k_gemm(const short* __restrict__ A,
                                              const short* __restrict__ Bt,
                                              void* __restrict__ out, int mode) {
  __shared__ __align__(16) short lA[128 * 32];
  __shared__ __align__(16) short lB[128 * 32];
  const int bm = blockIdx.x * 128, bn = blockIdx.y * 128;
  const int lane = threadIdx.x & 63, w = threadIdx.x >> 6;
  const int wr = w >> 1, wc = w & 1;
  const int r = lane & 15, g = lane >> 4;
  const int lrow = lane >> 2;                       // staging row within 16-row chunk
  const int lsl  = (lane & 3) ^ ((lane >> 3) & 3);  // pre-swizzled global k-slot
  const int rsw  = (r >> 1) & 3;                    // read-side swizzle

  f32x4 acc[4][4] = {};
  const short* Ab = A + (size_t)bm * DMc;
  const short* Bb = Bt + (size_t)bn * DMc;

  for (int k0 = 0; k0 < DMc; k0 += 32) {
    __syncthreads();
    #pragma unroll
    for (int c = 0; c < 2; c++) {
      const int rbase = c * 64 + w * 16;
      gload16(Ab + (size_t)(rbase + lrow) * DMc + k0 + lsl * 8, lA + rbase * 32);
      gload16(Bb + (size_t)(rbase + lrow) * DMc + k0 + lsl * 8, lB + rbase * 32);
    }
    __syncthreads();

    bf16x8 af[4], bfr[4];
    #pragma unroll
    for (int i = 0; i < 4; i++) {
      const int arow = wr * 64 + i * 16 + r;
      af[i]  = *reinterpret_cast<const bf16x8*>(lA + arow * 32 + (g ^ rsw) * 8);
      const int brow = wc * 64 + i * 16 + r;
      bfr[i] = *reinterpret_cast<const bf16x8*>(lB + brow * 32 + (g ^ rsw) * 8);
    }
    #pragma unroll
    for (int i = 0; i < 4; i++)
      #pragma unroll
      for (int n = 0; n < 4; n++) acc[i][n] = mfma16(af[i], bfr[n], acc[i][n]);
  }

  #pragma unroll
  for (int i = 0; i < 4; i++) {
    #pragma unroll
    for (int n = 0; n < 4; n++) {
      const int col = bn + wc * 64 + n * 16 + r;
      #pragma unroll
      for (int j = 0; j < 4; j++) {
        const int m = bm + wr * 64 + i * 16 + g * 4 + j;
        if (mode == 2) {
          reinterpret_cast<float*>(out)[(size_t)m * DMc + col] = acc[i][n][j];
        } else {
          const int b = m >> 11, s = m & (Sc - 1);
          const int h = col >> 6, d = col & (DHc - 1);
          size_t idx = (mode == 1)
              ? ((size_t)(b * Hc + h) * DHc + d) * Sc + s     // Vt [BH][64][S]
              : ((size_t)(b * Hc + h) * Sc + s) * DHc + d;    // Q/K [BH][S][64]
          reinterpret_cast<short*>(out)[idx] = f2bf(acc[i][n][j]);
        }
      }
    }
  }
}

// ---------------- fused scores + mask + softmax + attn-write + PV ----------------
// grid (S/16, BH), block 512 (8 waves). Block: 16 q-rows, full 2048 k-cols.
// SWAPPED QK^T (mfma(K,Q)): lane (r,g) holds S[q=qb+r][k=w*256+t*16+g*4+j] —
// 4 consecutive k per q-row per lane -> float4 attn stores, per-lane mask words,
// and a cheap per-wave LDS transpose of P (bf16, XOR-swizzled) feeding PV.
__global__ __launch_bounds__(512, 4) void k_attn(const short* __restrict__ Qb,
                                                 const short* __restrict__ Kb,
                                                 const uint32_t* __restrict__ pbits,
                                                 const short* __restrict__ Vt,
                                                 float* __restrict__ attn,
                                                 short* __restrict__ ctx) {
  __shared__ __align__(16) short pbuf[8][4096];  // 64 KiB: per-wave 16x256 bf16 P
  __shared__ float redm[8][16];
  __shared__ float reds[8][16];
  // rbuf (33.3 KiB) aliases pbuf; used only after a full __syncthreads()
  float (*rbuf)[16][65] = reinterpret_cast<float (*)[16][65]>(&pbuf[0][0]);

  const int qb = blockIdx.x * 16;
  const int bh = blockIdx.y;
  const int b = bh >> 4, h = bh & 15;
  const int lane = threadIdx.x & 63, w = threadIdx.x >> 6;
  const int r = lane & 15, g = lane >> 4;

  // Q B-fragment: lane(r,g) = Q[qb+r][g*8..g*8+7] (+32 for second half)
  const short* qrow = Qb + ((size_t)bh * Sc + qb + r) * DHc;
  const bf16x8 qf0 = *reinterpret_cast<const bf16x8*>(qrow + g * 8);
  const bf16x8 qf1 = *reinterpret_cast<const bf16x8*>(qrow + g * 8 + 32);
  const short* kbase = Kb + (size_t)bh * Sc * DHc;

  // swapped QK^T: A=K rows (k-cols), B=Q rows -> lane holds 4 consecutive k of q=qb+r
  f32x4 sc[16];
  #pragma unroll
  for (int t = 0; t < 16; t++) {
    const short* krow = kbase + (size_t)((w * 16 + t) * 16 + r) * DHc;
    bf16x8 kf0 = *reinterpret_cast<const bf16x8*>(krow + g * 8);
    bf16x8 kf1 = *reinterpret_cast<const bf16x8*>(krow + g * 8 + 32);
    f32x4 a = {};
    a = mfma16(kf0, qf0, a);
    a = mfma16(kf1, qf1, a);
    sc[t] = a;
  }

  // mask: row q=qb+r, words w*8..w*8+7 (32B contiguous per lane)
  const uint32_t* mrow = pbits + ((size_t)b * Sc + qb + r) * (Sc / 32) + w * 8;
  const uint4 m0 = *reinterpret_cast<const uint4*>(mrow);
  const uint4 m1 = *reinterpret_cast<const uint4*>(mrow + 4);
  const uint32_t mw[8] = {m0.x, m0.y, m0.z, m0.w, m1.x, m1.y, m1.z, m1.w};
  #pragma unroll
  for (int t = 0; t < 16; t++) {
    #pragma unroll
    for (int j = 0; j < 4; j++) {
      // k = w*256 + t*16 + g*4 + j ; word = t>>1 ; bit = (t&1)*16 + g*4 + j
      if ((mw[t >> 1] >> ((t & 1) * 16 + g * 4 + j)) & 1u) sc[t][j] = -8e9f;
    }
  }

  // row max: in-lane (64 vals) + cross-g shuffles + cross-wave LDS
  float pm = -3e38f;
  #pragma unroll
  for (int t = 0; t < 16; t++)
    #pragma unroll
    for (int j = 0; j < 4; j++) pm = fmaxf(pm, sc[t][j]);
  pm = fmaxf(pm, __shfl_xor(pm, 16));
  pm = fmaxf(pm, __shfl_xor(pm, 32));
  if (lane < 16) redm[w][r] = pm;
  __syncthreads();
  float rmax = redm[0][r];
  #pragma unroll
  for (int ww = 1; ww < 8; ww++) rmax = fmaxf(rmax, redm[ww][r]);

  // exp (scale folded into arg) + row sum
  float psum = 0.f;
  #pragma unroll
  for (int t = 0; t < 16; t++)
    #pragma unroll
    for (int j = 0; j < 4; j++) {
      float e = __expf((sc[t][j] - rmax) * 0.125f);
      sc[t][j] = e;
      psum += e;
    }
  psum += __shfl_xor(psum, 16);
  psum += __shfl_xor(psum, 32);
  if (lane < 16) reds[w][r] = psum;
  __syncthreads();
  float rsum = 0.f;
  #pragma unroll
  for (int ww = 0; ww < 8; ww++) rsum += reds[ww][r];
  const float rinv = 1.0f / rsum;

  // attn store (nontemporal f32x4) + normalized P -> LDS (bf16, XOR swizzle)
  float* arow_out = attn + ((size_t)bh * Sc + qb + r) * Sc + w * 256;
  #pragma unroll
  for (int t = 0; t < 16; t++) {
    f32x4 o;
    o[0] = sc[t][0] * rinv; o[1] = sc[t][1] * rinv;
    o[2] = sc[t][2] * rinv; o[3] = sc[t][3] * rinv;
    __builtin_nontemporal_store(o, reinterpret_cast<f32x4*>(arow_out + t * 16 + g * 4));
    uint32_t lo = (uint32_t)(uint16_t)f2bf(o[0]) | ((uint32_t)(uint16_t)f2bf(o[1]) << 16);
    uint32_t hi = (uint32_t)(uint16_t)f2bf(o[2]) | ((uint32_t)(uint16_t)f2bf(o[3]) << 16);
    uint64_t pk = (uint64_t)lo | ((uint64_t)hi << 32);
    const int slot = (t * 4 + g) ^ r;  // conflict-free write swizzle
    *reinterpret_cast<uint64_t*>(&pbuf[w][r * 256 + slot * 4]) = pk;
  }

  // PV over this wave's k-window; A-frag from per-wave LDS (same-wave, lgkm-ordered)
  const short* vb = Vt + (size_t)bh * DHc * Sc + w * 256;
  f32x4 pacc[4] = {};
  #pragma unroll
  for (int kt = 0; kt < 8; kt++) {
    const int s0 = (kt * 8 + g * 2) ^ r;
    const int s1 = (kt * 8 + g * 2 + 1) ^ r;
    union { uint64_t q[2]; bf16x8 v; } u;
    u.q[0] = *reinterpret_cast<const uint64_t*>(&pbuf[w][r * 256 + s0 * 4]);
    u.q[1] = *reinterpret_cast<const uint64_t*>(&pbuf[w][r * 256 + s1 * 4]);
    const bf16x8 af = u.v;
    #pragma unroll
    for (int n = 0; n < 4; n++) {
      bf16x8 vf = *reinterpret_cast<const bf16x8*>(
          vb + (size_t)(n * 16 + r) * Sc + kt * 32 + g * 8);
      pacc[n] = mfma16(af, vf, pacc[n]);
    }
  }

  // cross-wave reduce of partial ctx[16][64]; rbuf aliases pbuf -> barrier first
  __syncthreads();
  #pragma unroll
  for (int n = 0; n < 4; n++)
    #pragma unroll
    for (int j = 0; j < 4; j++) rbuf[w][g * 4 + j][n * 16 + r] = pacc[n][j];
  __syncthreads();

  const int tq = threadIdx.x >> 5, td = (threadIdx.x & 31) * 2;
  float s0 = 0.f, s1 = 0.f;
  #pragma unroll
  for (int ww = 0; ww < 8; ww++) {
    s0 += rbuf[ww][tq][td];
    s1 += rbuf[ww][tq][td + 1];
  }
  uint32_t pk = (uint32_t)(uint16_t)f2bf(s0) | ((uint32_t)(uint16_t)f2bf(s1) << 16);
  *reinterpret_cast<uint32_t*>(ctx + ((size_t)b * Sc + qb + tq) * DMc + h * DHc + td) = pk;
}

// ---------------- residual + LayerNorm ----------------
__global__ __launch_bounds__(256) void k_ln(const float* __restrict__ y,
                                            const float* __restrict__ resid,
                                            float* __restrict__ out) {
  const int m = blockIdx.x, t = threadIdx.x;
  const float4 a = reinterpret_cast<const float4*>(y + (size_t)m * DMc)[t];
  const float4 b = reinterpret_cast<const float4*>(resid + (size_t)m * DMc)[t];
  float x0 = a.x + b.x, x1 = a.y + b.y, x2 = a.z + b.z, x3 = a.w + b.w;

  float s = x0 + x1 + x2 + x3;
  #pragma unroll
  for (int m2 = 1; m2 < 64; m2 <<= 1) s += __shfl_xor(s, m2);
  __shared__ float red[4];
  __shared__ float red2[4];
  const int w = t >> 6, lane = t & 63;
  if (lane == 0) red[w] = s;
  __syncthreads();
  const float mean = (red[0] + red[1] + red[2] + red[3]) * (1.0f / DMc);

  x0 -= mean; x1 -= mean; x2 -= mean; x3 -= mean;
  float s2 = x0 * x0 + x1 * x1 + x2 * x2 + x3 * x3;
  #pragma unroll
  for (int m2 = 1; m2 < 64; m2 <<= 1) s2 += __shfl_xor(s2, m2);
  if (lane == 0) red2[w] = s2;
  __syncthreads();
  const float var = (red2[0] + red2[1] + red2[2] + red2[3]) * (1.0f / DMc);
  const float rstd = rsqrtf(var + 1e-5f);

  float4 o;
  o.x = x0 * rstd; o.y = x1 * rstd; o.z = x2 * rstd; o.w = x3 * rstd;
  reinterpret_cast<float4*>(out + (size_t)m * DMc)[t] = o;
}

extern "C" void kernel_launch(void* const* d_in, const int* in_sizes, int n_in,
                              void* d_out, int out_size, void* d_ws, size_t ws_size,
                              hipStream_t stream) {
  const float* inQ = (const float*)d_in[0];
  const float* inK = (const float*)d_in[1];
  const float* inV = (const float*)d_in[2];
  const int*   msk = (const int*)d_in[3];
  const float* WQ  = (const float*)d_in[4];
  const float* WK  = (const float*)d_in[5];
  const float* WV  = (const float*)d_in[6];
  const float* Wfc = (const float*)d_in[7];

  float* out_ln   = (float*)d_out;                       // [B,S,1024] f32
  float* out_attn = out_ln + (size_t)Bc * Sc * DMc;      // [B,H,S,S] f32

  const size_t NX = (size_t)Bc * Sc * DMc;  // 8,388,608
  const size_t NW = (size_t)DMc * DMc;      // 1,048,576
  short* ws = (short*)d_ws;
  short* XbQ = ws;                 // bf16 inputs
  short* XbK = XbQ + NX;
  short* XbV = XbK + NX;
  short* WQb = XbV + NX;           // bf16 weights
  short* WKb = WQb + NW;
  short* WVb = WKb + NW;
  short* Wfb = WVb + NW;
  short* Qb  = Wfb + NW;           // [BH][S][64]
  short* Kb  = Qb + NX;            // [BH][S][64]
  short* Vt  = Kb + NX;            // [BH][64][S]
  uint32_t* pbits = (uint32_t*)(Vt + NX);  // [B][S][64 words]
  short* ctx = XbV;                // aliases XbV (dead after V-proj)
  float* y   = (float*)XbQ;        // aliases XbQ+XbK (dead after Q/K-proj)

  // 1) f32 -> bf16 conversions + mask pack
  k_cvt<<<dim3((unsigned)(NX / 1024)), 256, 0, stream>>>(inQ, XbQ);
  k_cvt<<<dim3((unsigned)(NX / 1024)), 256, 0, stream>>>(inK, XbK);
  k_cvt<<<dim3((unsigned)(NX / 1024)), 256, 0, stream>>>(inV, XbV);
  k_cvt<<<dim3((unsigned)(NW / 1024)), 256, 0, stream>>>(WQ, WQb);
  k_cvt<<<dim3((unsigned)(NW / 1024)), 256, 0, stream>>>(WK, WKb);
  k_cvt<<<dim3((unsigned)(NW / 1024)), 256, 0, stream>>>(WV, WVb);
  k_cvt<<<dim3((unsigned)(NW / 1024)), 256, 0, stream>>>(Wfc, Wfb);
  k_pack<<<dim3((unsigned)(Bc * Sc * (Sc / 256))), 256, 0, stream>>>(msk, pbits);

  // 2) projections (128x128 tiles)
  dim3 gp(Bc * Sc / 128, DMc / 128);  // (64, 8)
  k_gemm<<<gp, 256, 0, stream>>>(XbQ, WQb, (void*)Qb, 0);
  k_gemm<<<gp, 256, 0, stream>>>(XbK, WKb, (void*)Kb, 0);
  k_gemm<<<gp, 256, 0, stream>>>(XbV, WVb, (void*)Vt, 1);

  // 3) fused scores + softmax + attn write + PV -> ctx
  k_attn<<<dim3(Sc / 16, BHc), 512, 0, stream>>>(Qb, Kb, pbits, Vt, out_attn, ctx);

  // 4) output projection -> y (f32)
  k_gemm<<<gp, 256, 0, stream>>>(ctx, Wfb, (void*)y, 2);

  // 5) residual + LayerNorm -> ln (output 0)
  k_ln<<<dim3(Bc * Sc), 256, 0, stream>>>(y, inQ, out_ln);
}